// Round 3
// baseline (275.771 us; speedup 1.0000x reference)
//
#include <hip/hip_runtime.h>

#define BS 4
#define SL 2048
#define NE 1024
#define NH 16
#define HD 64
#define N3 3072

typedef __attribute__((ext_vector_type(8))) __bf16 bf16x8;
typedef __attribute__((ext_vector_type(4))) float f32x4;
typedef __attribute__((ext_vector_type(4))) short s16x4;
typedef unsigned short u16;

__device__ __forceinline__ u16 f2bf(float f) {
  union { float f; unsigned int u; } v; v.f = f;
  unsigned int r = v.u + 0x7FFFu + ((v.u >> 16) & 1u);
  return (u16)(r >> 16);
}
// pack two floats -> dword of 2 bf16 (rtz), low = a, high = b
__device__ __forceinline__ int pack_bf2(float a, float b) {
  union { float f; unsigned int u; } x, y; x.f = a; y.f = b;
  return (int)((y.u & 0xFFFF0000u) | (x.u >> 16));
}

// global -> LDS direct 16B copy. LDS dest is WAVE-UNIFORM base; HW adds
// lane*16. Global address is per-lane.
__device__ __forceinline__ void gld16(const void* g, void* l) {
#if __has_builtin(__builtin_amdgcn_global_load_lds)
  __builtin_amdgcn_global_load_lds(
      (const __attribute__((address_space(1))) unsigned int*)g,
      (__attribute__((address_space(3))) unsigned int*)l, 16, 0, 0);
#else
  *(int4*)((char*)l + (size_t)(threadIdx.x & 63) * 16) = *(const int4*)g;
#endif
}

// counted vmcnt wait (compile-time literal)
template <int N>
__device__ __forceinline__ void vmw() {
  if constexpr (N == 0)
    asm volatile("s_waitcnt vmcnt(0)" ::: "memory");
  else if constexpr (N == 2)
    asm volatile("s_waitcnt vmcnt(2)" ::: "memory");
  else if constexpr (N == 3)
    asm volatile("s_waitcnt vmcnt(3)" ::: "memory");
  else if constexpr (N == 4)
    asm volatile("s_waitcnt vmcnt(4)" ::: "memory");
}

// ---------------- x fp32 -> bf16 ----------------
__global__ void convert_x(const float* __restrict__ x, u16* __restrict__ xb) {
  int i = (blockIdx.x * 256 + threadIdx.x) * 8;
  float4 f0 = *(const float4*)(x + i);
  float4 f1 = *(const float4*)(x + i + 4);
  union { int4 v; u16 h[8]; } p;
  p.h[0] = f2bf(f0.x); p.h[1] = f2bf(f0.y);
  p.h[2] = f2bf(f0.z); p.h[3] = f2bf(f0.w);
  p.h[4] = f2bf(f1.x); p.h[5] = f2bf(f1.y);
  p.h[6] = f2bf(f1.z); p.h[7] = f2bf(f1.w);
  *(int4*)(xb + i) = p.v;
}

// ---------------- W transpose+convert: Wt[n*K+k] = bf16(W[k*N+n]) ----------
__global__ void transpose_w(const float* __restrict__ W, u16* __restrict__ Wt,
                            int K, int N) {
  __shared__ u16 tile[32][33];
  int bn = blockIdx.x * 32, bk = blockIdx.y * 32;
  int tx = threadIdx.x, ty = threadIdx.y;  // blockDim = (32, 8)
  for (int r = 0; r < 32; r += 8)
    tile[ty + r][tx] = f2bf(W[(size_t)(bk + ty + r) * N + bn + tx]);
  __syncthreads();
  for (int r = 0; r < 32; r += 8)
    Wt[(size_t)(bn + ty + r) * K + bk + tx] = tile[tx][ty + r];
}

// ================= 8-phase 256-wide GEMM (m201 template, exact skeleton) ====
// C[M,N] = A[M,K] @ Bt[N,K]^T + bias[N].  BM=256, BK=64, BN in {256,128}.
// 8 waves (2m x 4n), double-buffered LDS, per phase:
//   { ds_read frags ; stage next chunk }   <- issued BEFORE barrier (latency
//   s_barrier                                 hides behind arrival spread)
//   s_waitcnt lgkmcnt(0) ; sched_barrier
//   setprio(1) 16 MFMA setprio(0)
//   s_waitcnt vmcnt(N)                     <- counted, covers NEXT phase's
//   s_barrier                                 chunk; barrier publishes it
// Chunk order per tile: A0,B0,B1,A1 (one per phase). Consumption: ph0 reads
// A0+B0, ph1 B1, ph2 A1, ph3 none. Steady-state waits (per-wave outstanding
// ledger): BN=256 -> 4 at ph0/ph1/ph3-end; BN=128 -> 4/3/3. Tail drains
// 2 -> 0. Never vmcnt(0) mid-loop.
// LDS 16B-block XOR swizzle (blk ^= row&7) on BOTH sides (rule 21):
// pre-swizzled global source into linear gld16 dest + swizzled ds_read addr.
#define BARR_MID()                                      \
  do {                                                  \
    __builtin_amdgcn_s_barrier();                       \
    asm volatile("s_waitcnt lgkmcnt(0)" ::: "memory");  \
    __builtin_amdgcn_sched_barrier(0);                  \
  } while (0)
#define BARR_END()                                      \
  do {                                                  \
    __builtin_amdgcn_s_barrier();                       \
    __builtin_amdgcn_sched_barrier(0);                  \
  } while (0)
#define MFMA_G(a, b, c) \
  __builtin_amdgcn_mfma_f32_16x16x32_bf16(a, b, c, 0, 0, 0)

template <int C32, int BN>
__global__ __launch_bounds__(512, 2) void gemm8p(
    const u16* __restrict__ A, const u16* __restrict__ Bt,
    const float* __restrict__ bias, void* __restrict__ C, int M, int N, int K,
    int lda) {
  constexpr int BM = 256, BK = 64;
  constexpr int NF = BN / 64;    // per-wave n-frags: 4 or 2
  constexpr int NHALF = NF / 2;  // frags per n-half: 2 or 1
  constexpr int V0 = (BN == 256) ? 4 : 3;  // end-ph3: covers ph0 (A0,B0)
  constexpr int V1 = 4;                    // end-ph0: covers ph1 (B1)
  constexpr int V2 = (BN == 256) ? 4 : 3;  // end-ph1: covers ph2 (A1)
  __shared__ u16 As[2][BM * BK];  // 64 KB, swizzled 16B blocks
  __shared__ u16 Bs[2][BN * BK];  // 64|32 KB

  const int tid = threadIdx.x;
  const int w = tid >> 6, lane = tid & 63;
  const int lq = lane >> 4, lr = lane & 15;
  const int m0 = blockIdx.y * BM, n0 = blockIdx.x * BN;

  // staging source addresses (pre-swizzled col block so LDS(row, cb) holds
  // global block cb ^ (row&7); gld16 writes 8 rows x 128 B linearly)
  const int l8 = lane >> 3, lb = lane & 7;
  const int swz8 = ((lb ^ l8) * 8);  // elems
  const u16* gA = A + (size_t)(m0 + w * 16 + l8) * lda + swz8;
  const u16* gB =
      (BN == 256) ? Bt + (size_t)(n0 + w * 16 + l8) * K + swz8
                  : Bt + (size_t)(n0 + w * 8 + l8) * K + swz8;

#define STAGE_A(buf, half, gp)                                        \
  do {                                                                \
    gld16((gp) + (size_t)((half) * 128) * lda,                        \
          &As[buf][(half) * 8192 + (2 * w) * 512]);                   \
    gld16((gp) + (size_t)((half) * 128 + 8) * lda,                    \
          &As[buf][(half) * 8192 + (2 * w + 1) * 512]);               \
  } while (0)
#define STAGE_B(buf, half, gp)                                        \
  do {                                                                \
    if constexpr (BN == 256) {                                        \
      gld16((gp) + (size_t)((half) * 128) * K,                        \
            &Bs[buf][(half) * 8192 + (2 * w) * 512]);                 \
      gld16((gp) + (size_t)((half) * 128 + 8) * K,                    \
            &Bs[buf][(half) * 8192 + (2 * w + 1) * 512]);             \
    } else {                                                          \
      gld16((gp) + (size_t)((half) * 64) * K,                         \
            &Bs[buf][(half) * 4096 + w * 512]);                       \
    }                                                                 \
  } while (0)
// fragment reads (swizzled): row&7 == lr&7 for all fragment rows
#define READ_A(buf, half)                                                    \
  _Pragma("unroll") for (int i = 0; i < 4; i++) _Pragma("unroll") for (       \
      int ks = 0; ks < 2; ks++) {                                            \
    int row = (half) * 128 + (w >> 2) * 64 + i * 16 + lr;                    \
    a[i][ks] =                                                               \
        *(const bf16x8*)&As[buf][row * 64 + (((ks * 4 + lq) ^ (lr & 7)) * 8)]; \
  }
#define READ_B(buf, nh)                                                      \
  _Pragma("unroll") for (int jj = 0; jj < NHALF; jj++) _Pragma("unroll") for ( \
      int ks = 0; ks < 2; ks++) {                                            \
    int row = (BN == 256) ? ((nh) * 128 + (w & 3) * 32 + jj * 16 + lr)       \
                          : ((nh) * 64 + (w & 3) * 16 + lr);                 \
    bb[nh][jj][ks] =                                                         \
        *(const bf16x8*)&Bs[buf][row * 64 + (((ks * 4 + lq) ^ (lr & 7)) * 8)]; \
  }
#define MFMA_PHASE(ilo, nh)                                                  \
  do {                                                                       \
    __builtin_amdgcn_s_setprio(1);                                          \
    _Pragma("unroll") for (int i = 0; i < 4; i++) _Pragma("unroll") for (     \
        int jj = 0; jj < NHALF; jj++) _Pragma("unroll") for (int ks = 0;     \
                                                             ks < 2; ks++)   \
        acc[(ilo) + i][(nh)*NHALF + jj] = MFMA_G(                            \
            a[i][ks], bb[nh][jj][ks], acc[(ilo) + i][(nh)*NHALF + jj]);      \
    __builtin_amdgcn_s_setprio(0);                                          \
  } while (0)

  const f32x4 fzero = {0.f, 0.f, 0.f, 0.f};
  f32x4 acc[8][NF];
#pragma unroll
  for (int i = 0; i < 8; i++)
#pragma unroll
    for (int j = 0; j < NF; j++) acc[i][j] = fzero;

  const int KT = K / BK;
  // prologue: stage tile 0 into buf 0 (order A0,B0,B1,A1 matches loop);
  // wait first two chunks (A0,B0) landed, publish with a barrier.
  STAGE_A(0, 0, gA);
  STAGE_B(0, 0, gB);
  STAGE_B(0, 1, gB);
  STAGE_A(0, 1, gA);
  const u16* gAn = gA + BK;
  const u16* gBn = gB + BK;
  vmw<V0>();
  BARR_END();

  for (int T = 0; T < KT; T++) {
    const int cur = T & 1, nxt = cur ^ 1;
    const bool pf = (T + 1 < KT);
    bf16x8 a[4][2], bb[2][NHALF][2];
    // ---- phase 0: m-half0 x n-half0 (consumes A0,B0) ----
    READ_A(cur, 0);
    READ_B(cur, 0);
    if (pf) STAGE_A(nxt, 0, gAn);
    BARR_MID();
    MFMA_PHASE(0, 0);
    if (pf) vmw<V1>(); else vmw<2>();
    BARR_END();
    // ---- phase 1: m-half0 x n-half1 (consumes B1) ----
    READ_B(cur, 1);
    if (pf) STAGE_B(nxt, 0, gBn);
    BARR_MID();
    MFMA_PHASE(0, 1);
    if (pf) vmw<V2>(); else vmw<0>();
    BARR_END();
    // ---- phase 2: m-half1 x n-half1 (consumes A1) ----
    READ_A(cur, 1);
    if (pf) STAGE_B(nxt, 1, gBn);
    BARR_MID();
    MFMA_PHASE(4, 1);
    BARR_END();
    // ---- phase 3: m-half1 x n-half0 (all regs resident) ----
    if (pf) STAGE_A(nxt, 1, gAn);
    BARR_MID();
    MFMA_PHASE(4, 0);
    if (pf) vmw<V0>();
    BARR_END();
    gAn += BK;
    gBn += BK;
  }

  // epilogue. C/D layout: col = lane&15, row = (lane>>4)*4 + reg.
#pragma unroll
  for (int j = 0; j < NF; j++) {
    int col;
    if (BN == 256)
      col = n0 + (j >> 1) * 128 + (w & 3) * 32 + (j & 1) * 16 + lr;
    else
      col = n0 + j * 64 + (w & 3) * 16 + lr;
    float bv = bias[col];
#pragma unroll
    for (int i = 0; i < 8; i++) {
      int rbase = m0 + (i >> 2) * 128 + (w >> 2) * 64 + (i & 3) * 16 + lq * 4;
#pragma unroll
      for (int r = 0; r < 4; r++) {
        float val = acc[i][j][r] + bv;
        if (C32) ((float*)C)[(size_t)(rbase + r) * N + col] = val;
        else     ((u16*)C)[(size_t)(rbase + r) * N + col]   = f2bf(val);
      }
    }
  }
#undef STAGE_A
#undef STAGE_B
#undef READ_A
#undef READ_B
#undef MFMA_PHASE
}

// ---------------- Flash attention (causal), paired q-tiles ----------------
// (unchanged — swapped QK^T, in-register P, O^T PV, defer-max)
#define KSTR 72  // 64 + 8 pad elems (rows 16B aligned)
#define MFMA16(a, b, c) __builtin_amdgcn_mfma_f32_16x16x32_bf16(a, b, c, 0, 0, 0)
#define MFMA1616(a, b, c) \
  __builtin_amdgcn_mfma_f32_16x16x16bf16_1k(a, b, c, 0, 0, 0)

__device__ __forceinline__ void attn_step(const bf16x8& q0, const bf16x8& q1,
                                          const u16* __restrict__ Kb,
                                          const u16* __restrict__ Vs,
                                          bool diag, int w, int lq, int lr,
                                          f32x4 (&o)[4], float& m_, float& l_) {
  const f32x4 fzero = {0.f, 0.f, 0.f, 0.f};
  const int swz = (lq ^ (lr & 3)) * 8;
  f32x4 s[4];
  __builtin_amdgcn_s_setprio(1);
#pragma unroll
  for (int j = 0; j < 4; j++) {
    int kr = j * 16 + lr;
    bf16x8 kf0 = *(const bf16x8*)&Kb[kr * 32 + swz];
    bf16x8 kf1 = *(const bf16x8*)&Kb[2048 + kr * 32 + swz];
    f32x4 z = MFMA16(kf0, q0, fzero);   // A=K, B=Q^T -> C = S^T
    s[j] = MFMA16(kf1, q1, z);
  }
  __builtin_amdgcn_s_setprio(0);
  // s[j][r] = S[q = lr][key = 16j + 4lq + r] (raw scores)
  if (diag) {
    int qloc = w * 16 + lr - 4 * lq;
#pragma unroll
    for (int j = 0; j < 4; j++)
#pragma unroll
      for (int r = 0; r < 4; r++)
        if (16 * j + r > qloc) s[j][r] = -1e30f;
  }
  // row max: in-lane over 16 regs, then across the 4-lane lq-group
  float mt = s[0][0];
#pragma unroll
  for (int j = 0; j < 4; j++)
#pragma unroll
    for (int r = 0; r < 4; r++) mt = fmaxf(mt, s[j][r]);
  mt = fmaxf(mt, __shfl_xor(mt, 16));
  mt = fmaxf(mt, __shfl_xor(mt, 32));
  // T13 defer-max: skip rescale while growth small (p bounded by e^8)
  float mn = m_;
  if (!__all(mt <= m_ + 64.0f)) {
    mn = fmaxf(m_, mt);
    float alpha = __expf((m_ - mn) * 0.125f);
    m_ = mn;
    l_ *= alpha;
#pragma unroll
    for (int jd = 0; jd < 4; jd++)
#pragma unroll
      for (int r = 0; r < 4; r++) o[jd][r] *= alpha;
  }
  // exp + pack P^T fragments fully in-register
  s16x4 pa[4];
  float psum = 0.f;
#pragma unroll
  for (int j = 0; j < 4; j++) {
    float p0 = __expf((s[j][0] - mn) * 0.125f);
    float p1 = __expf((s[j][1] - mn) * 0.125f);
    float p2 = __expf((s[j][2] - mn) * 0.125f);
    float p3 = __expf((s[j][3] - mn) * 0.125f);
    psum += (p0 + p1) + (p2 + p3);
    union { int i[2]; s16x4 v; } pu;
    pu.i[0] = pack_bf2(p0, p1);
    pu.i[1] = pack_bf2(p2, p3);
    pa[j] = pu.v;
  }
  l_ += psum;  // per-lane partial (this lane's k-quarter); reduced in epilogue
  // PV: O^T[d][q]. A = V^T (LDS), B = P^T (regs).
  __builtin_amdgcn_s_setprio(1);
#pragma unroll
  for (int jd = 0; jd < 4; jd++) {
    const u16* vrow = &Vs[(jd * 16 + lr) * KSTR + lq * 16];
    union { int4 q; s16x4 h[2]; } va, vb;
    va.q = *(const int4*)vrow;        // keys 4lq+r (j=0), 16+4lq+r (j=1)
    vb.q = *(const int4*)(vrow + 8);  // j=2, j=3
    o[jd] = MFMA1616(va.h[0], pa[0], o[jd]);
    o[jd] = MFMA1616(va.h[1], pa[1], o[jd]);
    o[jd] = MFMA1616(vb.h[0], pa[2], o[jd]);
    o[jd] = MFMA1616(vb.h[1], pa[3], o[jd]);
  }
  __builtin_amdgcn_s_setprio(0);
}

__global__ __launch_bounds__(256, 4) void attn_paired(u16* __restrict__ qkv) {
  __shared__ u16 Ks[2][4096];    // [key*32 + swz d-blk], d-half at +2048
  __shared__ u16 Vs[64 * KSTR];  // V^T [d][k'], key axis permuted

  const int tid = threadIdx.x;
  const int w = tid >> 6, lane = tid & 63;
  const int lq = lane >> 4, lr = lane & 15;
  const int bh = blockIdx.x, p = blockIdx.y;
  const int h = bh & (NH - 1), b = bh >> 4;
  const int qt0 = p, qt1 = (SL / 64 - 1) - p;

  u16* base = qkv + (size_t)b * SL * N3;
  const u16* kbase = base + NE + h * HD;  // K plane; V plane at +NE

  const int kg_key = lane >> 2;                  // key within 16-group
  const int kg_blk = (lane & 3) ^ (kg_key & 3);  // source d-block (swz)
  const int skey = tid & 63, sd0 = (tid >> 6) * 8;
  const int skeyP = ((skey >> 2) & 3) * 16 + (skey >> 4) * 4 + (skey & 3);
  const u16* vrow0 = base + (size_t)skey * N3 + 2 * NE + h * HD + sd0;

#define KPRE(buf, key0)                                                     \
  {                                                                         \
    _Pragma("unroll") for (int t = 0; t < 2; t++) {                         \
      int chunk = w * 2 + t, half = chunk >> 2, kgrp = chunk & 3;           \
      const u16* g = kbase + (size_t)((key0) + kgrp * 16 + kg_key) * N3 +   \
                     half * 32 + kg_blk * 8;                                \
      gld16(g, &Ks[buf][half * 2048 + kgrp * 512]);                         \
    }                                                                       \
  }

  bf16x8 qf[2][2];
#pragma unroll
  for (int half = 0; half < 2; half++) {
    int qt = half ? qt1 : qt0;
    const u16* qrow = base + (size_t)(qt * 64 + w * 16 + lr) * N3 + h * HD;
    qf[half][0] = *(const bf16x8*)(qrow + lq * 8);
    qf[half][1] = *(const bf16x8*)(qrow + 32 + lq * 8);
  }

  const f32x4 fzero = {0.f, 0.f, 0.f, 0.f};
  f32x4 o[2][4];
  float m_[2], l_[2];
#pragma unroll
  for (int half = 0; half < 2; half++) {
    m_[half] = -1e30f;
    l_[half] = 0.f;
#pragma unroll
    for (int jd = 0; jd < 4; jd++) o[half][jd] = fzero;
  }

  // prologue: K(0) async -> Ks[0]; V(0) -> static regs
  KPRE(0, 0);
  int4 v0 = *(const int4*)vrow0;
  int4 v1 = *(const int4*)(vrow0 + 32);

  const int ktend = qt1 + 1;
  for (int kt = 0; kt < ktend; kt++) {
    __syncthreads();  // readers of tile kt-1 done; drains K(kt) async + v regs
    {  // V(kt) regs -> LDS transposed (permuted key column)
      union { int4 v; u16 u[8]; } t0, t1;
      t0.v = v0; t1.v = v1;
#pragma unroll
      for (int j = 0; j < 8; j++) {
        Vs[(sd0 + j) * KSTR + skeyP] = t0.u[j];
        Vs[(sd0 + 32 + j) * KSTR + skeyP] = t1.u[j];
      }
    }
    __syncthreads();  // LDS(kt) ready

    if (kt + 1 < ktend) {  // prefetch kt+1; hidden by compute below
      KPRE((kt + 1) & 1, (kt + 1) * 64);
      const u16* nv = vrow0 + (size_t)(kt + 1) * 64 * N3;
      v0 = *(const int4*)nv;
      v1 = *(const int4*)(nv + 32);
    }

    const u16* Kb = &Ks[kt & 1][0];
    attn_step(qf[1][0], qf[1][1], Kb, Vs, kt == qt1, w, lq, lr, o[1], m_[1],
              l_[1]);
    if (kt <= qt0)
      attn_step(qf[0][0], qf[0][1], Kb, Vs, kt == qt0, w, lq, lr, o[0], m_[0],
                l_[0]);
  }

  // epilogue: reduce per-lane l partials, write Y over the Q slot
#pragma unroll
  for (int half = 0; half < 2; half++) {
    int qt = half ? qt1 : qt0;
    float lsum = l_[half];
    lsum += __shfl_xor(lsum, 16);
    lsum += __shfl_xor(lsum, 32);
    float inv = 1.0f / lsum;
    u16* yrow = base + (size_t)(qt * 64 + w * 16 + lr) * N3 + h * HD;
#pragma unroll
    for (int jd = 0; jd < 4; jd++) {
      int2 val;
      val.x = (int)(((unsigned)f2bf(o[half][jd][1] * inv) << 16) |
                    f2bf(o[half][jd][0] * inv));
      val.y = (int)(((unsigned)f2bf(o[half][jd][3] * inv) << 16) |
                    f2bf(o[half][jd][2] * inv));
      *(int2*)(yrow + 16 * jd + 4 * lq) = val;
    }
  }
}

// ---------------- host launch ----------------
extern "C" void kernel_launch(void* const* d_in, const int* in_sizes, int n_in,
                              void* d_out, int out_size, void* d_ws,
                              size_t ws_size, hipStream_t stream) {
  const float* x    = (const float*)d_in[0];
  const float* Wqkv = (const float*)d_in[2];
  const float* bqkv = (const float*)d_in[3];
  const float* Wo   = (const float*)d_in[4];
  const float* bo   = (const float*)d_in[5];

  u16* WqkvT  = (u16*)d_ws;                       // [3072,1024] bf16
  u16* WoT    = WqkvT + (size_t)N3 * NE;          // [1024,1024] bf16
  u16* xb     = WoT + (size_t)NE * NE;            // [8192,1024] bf16
  u16* qkvbuf = xb + (size_t)BS * SL * NE;        // [8192,3072] bf16

  convert_x<<<(BS * SL * NE) / (256 * 8), 256, 0, stream>>>(x, xb);
  transpose_w<<<dim3(N3 / 32, NE / 32), dim3(32, 8), 0, stream>>>(Wqkv, WqkvT,
                                                                  NE, N3);
  transpose_w<<<dim3(NE / 32, NE / 32), dim3(32, 8), 0, stream>>>(Wo, WoT, NE,
                                                                  NE);
  gemm8p<0, 256><<<dim3(N3 / 256, (BS * SL) / 256), 512, 0, stream>>>(
      xb, WqkvT, bqkv, qkvbuf, BS * SL, N3, NE, NE);
  attn_paired<<<dim3(BS * NH, SL / 128), 256, 0, stream>>>(qkvbuf);
  gemm8p<1, 128><<<dim3(NE / 128, (BS * SL) / 256), 512, 0, stream>>>(
      qkvbuf, WoT, bo, d_out, BS * SL, NE, NE, N3);
}

// Round 4
// 262.384 us; speedup vs baseline: 1.0510x; 1.0510x over previous
//
#include <hip/hip_runtime.h>

#define BS 4
#define SL 2048
#define NE 1024
#define NH 16
#define HD 64
#define N3 3072

typedef __attribute__((ext_vector_type(8))) __bf16 bf16x8;
typedef __attribute__((ext_vector_type(4))) float f32x4;
typedef __attribute__((ext_vector_type(4))) short s16x4;
typedef unsigned short u16;

__device__ __forceinline__ u16 f2bf(float f) {
  union { float f; unsigned int u; } v; v.f = f;
  unsigned int r = v.u + 0x7FFFu + ((v.u >> 16) & 1u);
  return (u16)(r >> 16);
}
// pack two floats -> dword of 2 bf16 (rtz), low = a, high = b
__device__ __forceinline__ int pack_bf2(float a, float b) {
  union { float f; unsigned int u; } x, y; x.f = a; y.f = b;
  return (int)((y.u & 0xFFFF0000u) | (x.u >> 16));
}

// global -> LDS direct 16B copy. LDS dest is WAVE-UNIFORM base; HW adds
// lane*16. Global address is per-lane.
__device__ __forceinline__ void gld16(const void* g, void* l) {
#if __has_builtin(__builtin_amdgcn_global_load_lds)
  __builtin_amdgcn_global_load_lds(
      (const __attribute__((address_space(1))) unsigned int*)g,
      (__attribute__((address_space(3))) unsigned int*)l, 16, 0, 0);
#else
  *(int4*)((char*)l + (size_t)(threadIdx.x & 63) * 16) = *(const int4*)g;
#endif
}

// ---------------- x fp32 -> bf16 ----------------
__global__ void convert_x(const float* __restrict__ x, u16* __restrict__ xb) {
  int i = (blockIdx.x * 256 + threadIdx.x) * 8;
  float4 f0 = *(const float4*)(x + i);
  float4 f1 = *(const float4*)(x + i + 4);
  union { int4 v; u16 h[8]; } p;
  p.h[0] = f2bf(f0.x); p.h[1] = f2bf(f0.y);
  p.h[2] = f2bf(f0.z); p.h[3] = f2bf(f0.w);
  p.h[4] = f2bf(f1.x); p.h[5] = f2bf(f1.y);
  p.h[6] = f2bf(f1.z); p.h[7] = f2bf(f1.w);
  *(int4*)(xb + i) = p.v;
}

// ---------------- W transpose+convert: Wt[n*K+k] = bf16(W[k*N+n]) ----------
__global__ void transpose_w(const float* __restrict__ W, u16* __restrict__ Wt,
                            int K, int N) {
  __shared__ u16 tile[32][33];
  int bn = blockIdx.x * 32, bk = blockIdx.y * 32;
  int tx = threadIdx.x, ty = threadIdx.y;  // blockDim = (32, 8)
  for (int r = 0; r < 32; r += 8)
    tile[ty + r][tx] = f2bf(W[(size_t)(bk + ty + r) * N + bn + tx]);
  __syncthreads();
  for (int r = 0; r < 32; r += 8)
    Wt[(size_t)(bn + ty + r) * K + bk + tx] = tile[tx][ty + r];
}

// ============ loose 2-block/CU GEMM (minimum-2-phase T3 recipe) ============
// C[M,N] = A[M,K] @ Bt[N,K]^T + bias[N].  BM=BN=128, BK=64, 4 waves (2m x 2n),
// double-buffered LDS (64 KB -> 2 blocks/CU: cross-block TLP covers the
// sync/stage stalls, the lever the lockstep 256^2 variants lacked).
// Per K-tile: { STAGE(T+1 -> other buf); reads(cur)+MFMA compiler-scheduled;
// __syncthreads() }. The syncthreads' vmcnt(0) is ledger-exact: it drains
// loads issued one full tile body (~2500 cy) earlier, > HBM latency, so the
// stage is hidden (vs r1's exposed sync;stage;sync). One barrier per tile.
// LDS 16B-block XOR swizzle (blk ^= row&7) on BOTH sides: pre-swizzled
// global source feeding linear gld16 dest + swizzled ds_read addresses.
// Grid exactly CU-quantized; bijective XCD-chunked blockIdx swizzle (T1).
#define MFMA_G(a, b, c) \
  __builtin_amdgcn_mfma_f32_16x16x32_bf16(a, b, c, 0, 0, 0)

template <int C32>
__global__ __launch_bounds__(256, 2) void gemm2b(
    const u16* __restrict__ A, const u16* __restrict__ Bt,
    const float* __restrict__ bias, void* __restrict__ C, int M, int N, int K,
    int lda) {
  constexpr int BM = 128, BN = 128, BK = 64;
  __shared__ u16 As[2][BM * BK];  // 16 KB each
  __shared__ u16 Bs[2][BN * BK];

  const int tid = threadIdx.x;
  const int w = tid >> 6, lane = tid & 63;
  const int lq = lane >> 4, lr = lane & 15;
  // XCD-chunked bijective swizzle (nwg % 8 == 0 for both instantiations)
  const int nwx = gridDim.x;
  const int nwg = nwx * gridDim.y;
  const int lin = blockIdx.y * nwx + blockIdx.x;
  const int cpx = nwg >> 3;
  const int swb = (lin & 7) * cpx + (lin >> 3);
  const int m0 = (swb / nwx) * BM, n0 = (swb % nwx) * BN;
  const int wm = (w >> 1) * 64, wn = (w & 1) * 64;

  // staging source (pre-swizzled col block: LDS(row, cb) holds global block
  // cb ^ (row&7); each gld16 writes 8 rows x 128 B linearly)
  const int l8 = lane >> 3, lb = lane & 7;
  const int sw8 = (lb ^ l8) * 8;  // elems
  const u16* gA = A + (size_t)(m0 + w * 32 + l8) * lda + sw8;
  const u16* gB = Bt + (size_t)(n0 + w * 32 + l8) * K + sw8;

#define STAGE(buf, gpa, gpb)                                  \
  do {                                                        \
    _Pragma("unroll") for (int c = 0; c < 4; c++) {           \
      gld16((gpa) + (size_t)(c * 8) * lda,                    \
            &As[buf][(w * 32 + c * 8) * 64]);                 \
      gld16((gpb) + (size_t)(c * 8) * K,                      \
            &Bs[buf][(w * 32 + c * 8) * 64]);                 \
    }                                                         \
  } while (0)

  const f32x4 fzero = {0.f, 0.f, 0.f, 0.f};
  f32x4 acc[4][4];
#pragma unroll
  for (int i = 0; i < 4; i++)
#pragma unroll
    for (int j = 0; j < 4; j++) acc[i][j] = fzero;

  const int KT = K / BK;
  STAGE(0, gA, gB);  // prologue
  __syncthreads();   // per-wave vmcnt(0) + barrier: buf0 ready
  const u16* gAn = gA + BK;
  const u16* gBn = gB + BK;

  for (int T = 0; T < KT; T++) {
    const int cur = T & 1;
    if (T + 1 < KT) {  // prefetch next tile into other buffer (async DMA,
      STAGE(cur ^ 1, gAn, gBn);  // hidden under this tile's compute)
      gAn += BK;
      gBn += BK;
    }
    __builtin_amdgcn_sched_barrier(0);  // keep stage issue first

    bf16x8 a[4][2], bfr[4][2];
#pragma unroll
    for (int i = 0; i < 4; i++)
#pragma unroll
      for (int ks = 0; ks < 2; ks++) {
        int row = wm + i * 16 + lr;
        a[i][ks] = *(const bf16x8*)
            &As[cur][row * 64 + (((ks * 4 + lq) ^ (lr & 7)) * 8)];
      }
#pragma unroll
    for (int j = 0; j < 4; j++)
#pragma unroll
      for (int ks = 0; ks < 2; ks++) {
        int row = wn + j * 16 + lr;
        bfr[j][ks] = *(const bf16x8*)
            &Bs[cur][row * 64 + (((ks * 4 + lq) ^ (lr & 7)) * 8)];
      }
    __builtin_amdgcn_s_setprio(1);
#pragma unroll
    for (int ks = 0; ks < 2; ks++)
#pragma unroll
      for (int i = 0; i < 4; i++)
#pragma unroll
        for (int j = 0; j < 4; j++)
          acc[i][j] = MFMA_G(a[i][ks], bfr[j][ks], acc[i][j]);
    __builtin_amdgcn_s_setprio(0);
    __syncthreads();  // vmcnt(0)+lgkm(0)+barrier: next buf published
  }
#undef STAGE

  // epilogue. C/D layout: col = lane&15, row = (lane>>4)*4 + reg.
#pragma unroll
  for (int j = 0; j < 4; j++) {
    int col = n0 + wn + j * 16 + lr;
    float bv = bias[col];
#pragma unroll
    for (int i = 0; i < 4; i++) {
#pragma unroll
      for (int r = 0; r < 4; r++) {
        int row = m0 + wm + i * 16 + lq * 4 + r;
        float val = acc[i][j][r] + bv;
        if (C32) ((float*)C)[(size_t)row * N + col] = val;
        else     ((u16*)C)[(size_t)row * N + col]   = f2bf(val);
      }
    }
  }
}

// ---------------- Flash attention (causal), paired q-tiles ----------------
// (unchanged — swapped QK^T, in-register P, O^T PV, defer-max)
#define KSTR 72  // 64 + 8 pad elems (rows 16B aligned)
#define MFMA16(a, b, c) __builtin_amdgcn_mfma_f32_16x16x32_bf16(a, b, c, 0, 0, 0)
#define MFMA1616(a, b, c) \
  __builtin_amdgcn_mfma_f32_16x16x16bf16_1k(a, b, c, 0, 0, 0)

__device__ __forceinline__ void attn_step(const bf16x8& q0, const bf16x8& q1,
                                          const u16* __restrict__ Kb,
                                          const u16* __restrict__ Vs,
                                          bool diag, int w, int lq, int lr,
                                          f32x4 (&o)[4], float& m_, float& l_) {
  const f32x4 fzero = {0.f, 0.f, 0.f, 0.f};
  const int swz = (lq ^ (lr & 3)) * 8;
  f32x4 s[4];
  __builtin_amdgcn_s_setprio(1);
#pragma unroll
  for (int j = 0; j < 4; j++) {
    int kr = j * 16 + lr;
    bf16x8 kf0 = *(const bf16x8*)&Kb[kr * 32 + swz];
    bf16x8 kf1 = *(const bf16x8*)&Kb[2048 + kr * 32 + swz];
    f32x4 z = MFMA16(kf0, q0, fzero);   // A=K, B=Q^T -> C = S^T
    s[j] = MFMA16(kf1, q1, z);
  }
  __builtin_amdgcn_s_setprio(0);
  // s[j][r] = S[q = lr][key = 16j + 4lq + r] (raw scores)
  if (diag) {
    int qloc = w * 16 + lr - 4 * lq;
#pragma unroll
    for (int j = 0; j < 4; j++)
#pragma unroll
      for (int r = 0; r < 4; r++)
        if (16 * j + r > qloc) s[j][r] = -1e30f;
  }
  // row max: in-lane over 16 regs, then across the 4-lane lq-group
  float mt = s[0][0];
#pragma unroll
  for (int j = 0; j < 4; j++)
#pragma unroll
    for (int r = 0; r < 4; r++) mt = fmaxf(mt, s[j][r]);
  mt = fmaxf(mt, __shfl_xor(mt, 16));
  mt = fmaxf(mt, __shfl_xor(mt, 32));
  // T13 defer-max: skip rescale while growth small (p bounded by e^8)
  float mn = m_;
  if (!__all(mt <= m_ + 64.0f)) {
    mn = fmaxf(m_, mt);
    float alpha = __expf((m_ - mn) * 0.125f);
    m_ = mn;
    l_ *= alpha;
#pragma unroll
    for (int jd = 0; jd < 4; jd++)
#pragma unroll
      for (int r = 0; r < 4; r++) o[jd][r] *= alpha;
  }
  // exp + pack P^T fragments fully in-register
  s16x4 pa[4];
  float psum = 0.f;
#pragma unroll
  for (int j = 0; j < 4; j++) {
    float p0 = __expf((s[j][0] - mn) * 0.125f);
    float p1 = __expf((s[j][1] - mn) * 0.125f);
    float p2 = __expf((s[j][2] - mn) * 0.125f);
    float p3 = __expf((s[j][3] - mn) * 0.125f);
    psum += (p0 + p1) + (p2 + p3);
    union { int i[2]; s16x4 v; } pu;
    pu.i[0] = pack_bf2(p0, p1);
    pu.i[1] = pack_bf2(p2, p3);
    pa[j] = pu.v;
  }
  l_ += psum;  // per-lane partial (this lane's k-quarter); reduced in epilogue
  // PV: O^T[d][q]. A = V^T (LDS), B = P^T (regs).
  __builtin_amdgcn_s_setprio(1);
#pragma unroll
  for (int jd = 0; jd < 4; jd++) {
    const u16* vrow = &Vs[(jd * 16 + lr) * KSTR + lq * 16];
    union { int4 q; s16x4 h[2]; } va, vb;
    va.q = *(const int4*)vrow;        // keys 4lq+r (j=0), 16+4lq+r (j=1)
    vb.q = *(const int4*)(vrow + 8);  // j=2, j=3
    o[jd] = MFMA1616(va.h[0], pa[0], o[jd]);
    o[jd] = MFMA1616(va.h[1], pa[1], o[jd]);
    o[jd] = MFMA1616(vb.h[0], pa[2], o[jd]);
    o[jd] = MFMA1616(vb.h[1], pa[3], o[jd]);
  }
  __builtin_amdgcn_s_setprio(0);
}

__global__ __launch_bounds__(256, 4) void attn_paired(u16* __restrict__ qkv) {
  __shared__ u16 Ks[2][4096];    // [key*32 + swz d-blk], d-half at +2048
  __shared__ u16 Vs[64 * KSTR];  // V^T [d][k'], key axis permuted

  const int tid = threadIdx.x;
  const int w = tid >> 6, lane = tid & 63;
  const int lq = lane >> 4, lr = lane & 15;
  const int bh = blockIdx.x, p = blockIdx.y;
  const int h = bh & (NH - 1), b = bh >> 4;
  const int qt0 = p, qt1 = (SL / 64 - 1) - p;

  u16* base = qkv + (size_t)b * SL * N3;
  const u16* kbase = base + NE + h * HD;  // K plane; V plane at +NE

  const int kg_key = lane >> 2;                  // key within 16-group
  const int kg_blk = (lane & 3) ^ (kg_key & 3);  // source d-block (swz)
  const int skey = tid & 63, sd0 = (tid >> 6) * 8;
  const int skeyP = ((skey >> 2) & 3) * 16 + (skey >> 4) * 4 + (skey & 3);
  const u16* vrow0 = base + (size_t)skey * N3 + 2 * NE + h * HD + sd0;

#define KPRE(buf, key0)                                                     \
  {                                                                         \
    _Pragma("unroll") for (int t = 0; t < 2; t++) {                         \
      int chunk = w * 2 + t, half = chunk >> 2, kgrp = chunk & 3;           \
      const u16* g = kbase + (size_t)((key0) + kgrp * 16 + kg_key) * N3 +   \
                     half * 32 + kg_blk * 8;                                \
      gld16(g, &Ks[buf][half * 2048 + kgrp * 512]);                         \
    }                                                                       \
  }

  bf16x8 qf[2][2];
#pragma unroll
  for (int half = 0; half < 2; half++) {
    int qt = half ? qt1 : qt0;
    const u16* qrow = base + (size_t)(qt * 64 + w * 16 + lr) * N3 + h * HD;
    qf[half][0] = *(const bf16x8*)(qrow + lq * 8);
    qf[half][1] = *(const bf16x8*)(qrow + 32 + lq * 8);
  }

  const f32x4 fzero = {0.f, 0.f, 0.f, 0.f};
  f32x4 o[2][4];
  float m_[2], l_[2];
#pragma unroll
  for (int half = 0; half < 2; half++) {
    m_[half] = -1e30f;
    l_[half] = 0.f;
#pragma unroll
    for (int jd = 0; jd < 4; jd++) o[half][jd] = fzero;
  }

  // prologue: K(0) async -> Ks[0]; V(0) -> static regs
  KPRE(0, 0);
  int4 v0 = *(const int4*)vrow0;
  int4 v1 = *(const int4*)(vrow0 + 32);

  const int ktend = qt1 + 1;
  for (int kt = 0; kt < ktend; kt++) {
    __syncthreads();  // readers of tile kt-1 done; drains K(kt) async + v regs
    {  // V(kt) regs -> LDS transposed (permuted key column)
      union { int4 v; u16 u[8]; } t0, t1;
      t0.v = v0; t1.v = v1;
#pragma unroll
      for (int j = 0; j < 8; j++) {
        Vs[(sd0 + j) * KSTR + skeyP] = t0.u[j];
        Vs[(sd0 + 32 + j) * KSTR + skeyP] = t1.u[j];
      }
    }
    __syncthreads();  // LDS(kt) ready

    if (kt + 1 < ktend) {  // prefetch kt+1; hidden by compute below
      KPRE((kt + 1) & 1, (kt + 1) * 64);
      const u16* nv = vrow0 + (size_t)(kt + 1) * 64 * N3;
      v0 = *(const int4*)nv;
      v1 = *(const int4*)(nv + 32);
    }

    const u16* Kb = &Ks[kt & 1][0];
    attn_step(qf[1][0], qf[1][1], Kb, Vs, kt == qt1, w, lq, lr, o[1], m_[1],
              l_[1]);
    if (kt <= qt0)
      attn_step(qf[0][0], qf[0][1], Kb, Vs, kt == qt0, w, lq, lr, o[0], m_[0],
                l_[0]);
  }

  // epilogue: reduce per-lane l partials, write Y over the Q slot
#pragma unroll
  for (int half = 0; half < 2; half++) {
    int qt = half ? qt1 : qt0;
    float lsum = l_[half];
    lsum += __shfl_xor(lsum, 16);
    lsum += __shfl_xor(lsum, 32);
    float inv = 1.0f / lsum;
    u16* yrow = base + (size_t)(qt * 64 + w * 16 + lr) * N3 + h * HD;
#pragma unroll
    for (int jd = 0; jd < 4; jd++) {
      int2 val;
      val.x = (int)(((unsigned)f2bf(o[half][jd][1] * inv) << 16) |
                    f2bf(o[half][jd][0] * inv));
      val.y = (int)(((unsigned)f2bf(o[half][jd][3] * inv) << 16) |
                    f2bf(o[half][jd][2] * inv));
      *(int2*)(yrow + 16 * jd + 4 * lq) = val;
    }
  }
}

// ---------------- host launch ----------------
extern "C" void kernel_launch(void* const* d_in, const int* in_sizes, int n_in,
                              void* d_out, int out_size, void* d_ws,
                              size_t ws_size, hipStream_t stream) {
  const float* x    = (const float*)d_in[0];
  const float* Wqkv = (const float*)d_in[2];
  const float* bqkv = (const float*)d_in[3];
  const float* Wo   = (const float*)d_in[4];
  const float* bo   = (const float*)d_in[5];

  u16* WqkvT  = (u16*)d_ws;                       // [3072,1024] bf16
  u16* WoT    = WqkvT + (size_t)N3 * NE;          // [1024,1024] bf16
  u16* xb     = WoT + (size_t)NE * NE;            // [8192,1024] bf16
  u16* qkvbuf = xb + (size_t)BS * SL * NE;        // [8192,3072] bf16

  convert_x<<<(BS * SL * NE) / (256 * 8), 256, 0, stream>>>(x, xb);
  transpose_w<<<dim3(N3 / 32, NE / 32), dim3(32, 8), 0, stream>>>(Wqkv, WqkvT,
                                                                  NE, N3);
  transpose_w<<<dim3(NE / 32, NE / 32), dim3(32, 8), 0, stream>>>(Wo, WoT, NE,
                                                                  NE);
  gemm2b<0><<<dim3(N3 / 128, (BS * SL) / 128), 256, 0, stream>>>(
      xb, WqkvT, bqkv, qkvbuf, BS * SL, N3, NE, NE);
  attn_paired<<<dim3(BS * NH, SL / 128), 256, 0, stream>>>(qkvbuf);
  gemm2b<1><<<dim3(NE / 128, (BS * SL) / 128), 256, 0, stream>>>(
      qkvbuf, WoT, bo, d_out, BS * SL, NE, NE, N3);
}